// Round 1
// baseline (347.973 us; speedup 1.0000x reference)
//
#include <hip/hip_runtime.h>
#include <math.h>

#define H 4096
#define H4 (H / 4)          // 1024 float4 per row
#define T1 256              // threads per block (4 waves)
#define RPB 8               // rows per block (contiguous 128 KB slab)
#define NB1 (4 * H / RPB)   // 2048 row-blocks for the 4 GEMVs

__device__ __forceinline__ float wave_reduce_sum(float v) {
    #pragma unroll
    for (int off = 32; off > 0; off >>= 1)
        v += __shfl_down(v, off, 64);
    return v;
}

__device__ __forceinline__ float sigmoidf_(float x) {
    return 1.0f / (1.0f + __expf(-x));
}

__device__ __forceinline__ float dot4(float4 a, float4 b) {
    return a.x * b.x + a.y * b.y + a.z * b.z + a.w * b.w;
}

// Kernel 1: all four GEMVs + the two scalar-gate dot products.
// Block-cooperative: 256 threads per row, 8 consecutive rows per block,
// 2 rows in flight per step (8 float4 loads outstanding per thread).
// x is held in registers (16 VGPRs) for the whole block.
// Block NB1 (the extra one) computes the wi/wf dots.
__global__ __launch_bounds__(T1) void gemv_all(
    const float* __restrict__ x,
    const float* __restrict__ Wq, const float* __restrict__ Wk,
    const float* __restrict__ Wv, const float* __restrict__ Wo,
    const float* __restrict__ bq, const float* __restrict__ bk,
    const float* __restrict__ bv, const float* __restrict__ bo,
    const float* __restrict__ wi, const float* __restrict__ wf,
    float* __restrict__ q, float* __restrict__ k,
    float* __restrict__ v, float* __restrict__ og,
    float* __restrict__ s2)
{
    const int tid  = threadIdx.x;
    const int wave = tid >> 6;
    const int lane = tid & 63;

    __shared__ float red[2][4];

    const float4* x4 = (const float4*)x;
    // x in registers: thread t covers float4 indices t, t+256, t+512, t+768
    float4 xr0 = x4[tid];
    float4 xr1 = x4[tid + 256];
    float4 xr2 = x4[tid + 512];
    float4 xr3 = x4[tid + 768];

    if (blockIdx.x == NB1) {
        // wi and wf dot products (pair-processed like a row pair)
        const float4* a4 = (const float4*)wi;
        const float4* b4 = (const float4*)wf;
        float4 a0 = a4[tid], a1 = a4[tid + 256], a2 = a4[tid + 512], a3 = a4[tid + 768];
        float4 c0 = b4[tid], c1 = b4[tid + 256], c2 = b4[tid + 512], c3 = b4[tid + 768];
        float sa = dot4(a0, xr0) + dot4(a1, xr1) + dot4(a2, xr2) + dot4(a3, xr3);
        float sb = dot4(c0, xr0) + dot4(c1, xr1) + dot4(c2, xr2) + dot4(c3, xr3);
        sa = wave_reduce_sum(sa);
        sb = wave_reduce_sum(sb);
        if (lane == 0) { red[0][wave] = sa; red[1][wave] = sb; }
        __syncthreads();
        if (tid < 2) {
            float s = red[tid][0] + red[tid][1] + red[tid][2] + red[tid][3];
            s2[tid] = s;   // raw dots: s2[0]=wi.x, s2[1]=wf.x
        }
        return;
    }

    const int row0 = blockIdx.x * RPB;        // 0..16383, 8 rows, same matrix
    const int m = row0 >> 12;                 // which matrix (4096 % 8 == 0)
    const float* W    = (m == 0) ? Wq : (m == 1) ? Wk : (m == 2) ? Wv : Wo;
    const float* bias = (m == 0) ? bq : (m == 1) ? bk : (m == 2) ? bv : bo;
    const int rbase = row0 & (H - 1);

    #pragma unroll
    for (int rr = 0; rr < RPB; rr += 2) {
        const float4* a4 = (const float4*)(W + (size_t)(rbase + rr) * H);
        const float4* b4 = (const float4*)(W + (size_t)(rbase + rr + 1) * H);
        // 8 loads issued back-to-back -> deep in-flight queue
        float4 a0 = a4[tid], a1 = a4[tid + 256], a2 = a4[tid + 512], a3 = a4[tid + 768];
        float4 c0 = b4[tid], c1 = b4[tid + 256], c2 = b4[tid + 512], c3 = b4[tid + 768];

        float sa = dot4(a0, xr0) + dot4(a1, xr1) + dot4(a2, xr2) + dot4(a3, xr3);
        float sb = dot4(c0, xr0) + dot4(c1, xr1) + dot4(c2, xr2) + dot4(c3, xr3);
        sa = wave_reduce_sum(sa);
        sb = wave_reduce_sum(sb);
        if (lane == 0) { red[0][wave] = sa; red[1][wave] = sb; }
        __syncthreads();
        if (tid < 2) {
            const float s = red[tid][0] + red[tid][1] + red[tid][2] + red[tid][3];
            const int r = rbase + rr + tid;
            const float sbias = s + bias[r];
            if (m == 0)      q[r]  = sbias;
            else if (m == 1) k[r]  = sbias * 0.015625f;   // 1/sqrt(4096)
            else if (m == 2) v[r]  = sbias;
            else             og[r] = sigmoidf_(sbias);
        }
        __syncthreads();   // protect red[][] reuse
    }
}

// Kernel 2: C = f*C_prev + (i*v[r])*k  (written to C_out), and
// u[r] = C_prev[r,:] . q accumulated from the same loads.
// Same block-cooperative structure: 256 threads/row, 8 rows/block, row pairs.
__global__ __launch_bounds__(T1) void c_update(
    const float* __restrict__ C_prev,
    const float* __restrict__ q, const float* __restrict__ k,
    const float* __restrict__ v, const float* __restrict__ s2,
    const float* __restrict__ bi, const float* __restrict__ bf,
    float* __restrict__ C_out, float* __restrict__ u)
{
    const int tid  = threadIdx.x;
    const int wave = tid >> 6;
    const int lane = tid & 63;

    __shared__ float red[2][4];

    const float ig = __expf(s2[0] + bi[0]);
    const float fg = sigmoidf_(s2[1] + bf[0]);

    const float4* q4 = (const float4*)q;
    const float4* k4 = (const float4*)k;
    float4 qr0 = q4[tid], qr1 = q4[tid + 256], qr2 = q4[tid + 512], qr3 = q4[tid + 768];
    float4 kr0 = k4[tid], kr1 = k4[tid + 256], kr2 = k4[tid + 512], kr3 = k4[tid + 768];

    const int row0 = blockIdx.x * RPB;

    #pragma unroll
    for (int rr = 0; rr < RPB; rr += 2) {
        const int ra = row0 + rr;
        const int rb = ra + 1;
        const float iva = ig * v[ra];   // uniform -> scalar load
        const float ivb = ig * v[rb];

        const float4* ca4 = (const float4*)(C_prev + (size_t)ra * H);
        const float4* cb4 = (const float4*)(C_prev + (size_t)rb * H);
        float4*       oa4 = (float4*)(C_out + (size_t)ra * H);
        float4*       ob4 = (float4*)(C_out + (size_t)rb * H);

        float4 a0 = ca4[tid], a1 = ca4[tid + 256], a2 = ca4[tid + 512], a3 = ca4[tid + 768];
        float4 c0 = cb4[tid], c1 = cb4[tid + 256], c2 = cb4[tid + 512], c3 = cb4[tid + 768];

        float4 o;
        o.x = fg * a0.x + iva * kr0.x; o.y = fg * a0.y + iva * kr0.y;
        o.z = fg * a0.z + iva * kr0.z; o.w = fg * a0.w + iva * kr0.w;
        oa4[tid] = o;
        o.x = fg * a1.x + iva * kr1.x; o.y = fg * a1.y + iva * kr1.y;
        o.z = fg * a1.z + iva * kr1.z; o.w = fg * a1.w + iva * kr1.w;
        oa4[tid + 256] = o;
        o.x = fg * a2.x + iva * kr2.x; o.y = fg * a2.y + iva * kr2.y;
        o.z = fg * a2.z + iva * kr2.z; o.w = fg * a2.w + iva * kr2.w;
        oa4[tid + 512] = o;
        o.x = fg * a3.x + iva * kr3.x; o.y = fg * a3.y + iva * kr3.y;
        o.z = fg * a3.z + iva * kr3.z; o.w = fg * a3.w + iva * kr3.w;
        oa4[tid + 768] = o;

        o.x = fg * c0.x + ivb * kr0.x; o.y = fg * c0.y + ivb * kr0.y;
        o.z = fg * c0.z + ivb * kr0.z; o.w = fg * c0.w + ivb * kr0.w;
        ob4[tid] = o;
        o.x = fg * c1.x + ivb * kr1.x; o.y = fg * c1.y + ivb * kr1.y;
        o.z = fg * c1.z + ivb * kr1.z; o.w = fg * c1.w + ivb * kr1.w;
        ob4[tid + 256] = o;
        o.x = fg * c2.x + ivb * kr2.x; o.y = fg * c2.y + ivb * kr2.y;
        o.z = fg * c2.z + ivb * kr2.z; o.w = fg * c2.w + ivb * kr2.w;
        ob4[tid + 512] = o;
        o.x = fg * c3.x + ivb * kr3.x; o.y = fg * c3.y + ivb * kr3.y;
        o.z = fg * c3.z + ivb * kr3.z; o.w = fg * c3.w + ivb * kr3.w;
        ob4[tid + 768] = o;

        float sa = dot4(a0, qr0) + dot4(a1, qr1) + dot4(a2, qr2) + dot4(a3, qr3);
        float sb = dot4(c0, qr0) + dot4(c1, qr1) + dot4(c2, qr2) + dot4(c3, qr3);
        sa = wave_reduce_sum(sa);
        sb = wave_reduce_sum(sb);
        if (lane == 0) { red[0][wave] = sa; red[1][wave] = sb; }
        __syncthreads();
        if (tid < 2) {
            u[row0 + rr + tid] = red[tid][0] + red[tid][1] + red[tid][2] + red[tid][3];
        }
        __syncthreads();
    }
}

// Kernel 3: n = f*n_prev + i*k (written out); nq = n.q; kq = k.q;
// h = og * (f*u + i*v*kq) / max(|nq|,1). Single block.
__global__ __launch_bounds__(1024) void finalize(
    const float* __restrict__ n_prev,
    const float* __restrict__ q, const float* __restrict__ k,
    const float* __restrict__ v, const float* __restrict__ og,
    const float* __restrict__ u, const float* __restrict__ s2,
    const float* __restrict__ bi, const float* __restrict__ bf,
    float* __restrict__ h, float* __restrict__ n_out)
{
    const int t = threadIdx.x;
    const int wave = t >> 6;
    const int lane = t & 63;

    const float ig = __expf(s2[0] + bi[0]);
    const float fg = sigmoidf_(s2[1] + bf[0]);

    float nq = 0.0f, kq = 0.0f;
    for (int j = t; j < H; j += 1024) {
        float kj = k[j];
        float qj = q[j];
        float nj = fg * n_prev[j] + ig * kj;
        n_out[j] = nj;
        nq += nj * qj;
        kq += kj * qj;
    }
    nq = wave_reduce_sum(nq);
    kq = wave_reduce_sum(kq);

    __shared__ float snq[16], skq[16];
    if (lane == 0) { snq[wave] = nq; skq[wave] = kq; }
    __syncthreads();
    if (t == 0) {
        float a = 0.0f, b = 0.0f;
        #pragma unroll
        for (int w = 0; w < 16; ++w) { a += snq[w]; b += skq[w]; }
        snq[0] = a; skq[0] = b;
    }
    __syncthreads();

    const float denom = fmaxf(fabsf(snq[0]), 1.0f);
    const float kqv = skq[0];
    const float inv_denom = 1.0f / denom;

    for (int j = t; j < H; j += 1024) {
        float ht = (fg * u[j] + ig * v[j] * kqv) * inv_denom;
        h[j] = og[j] * ht;
    }
}

extern "C" void kernel_launch(void* const* d_in, const int* in_sizes, int n_in,
                              void* d_out, int out_size, void* d_ws, size_t ws_size,
                              hipStream_t stream) {
    const float* x      = (const float*)d_in[0];
    // d_in[1] = h_prev (unused by mLSTM math)
    const float* C_prev = (const float*)d_in[2];
    const float* n_prev = (const float*)d_in[3];
    const float* Wq     = (const float*)d_in[4];
    const float* Wk     = (const float*)d_in[5];
    const float* Wv     = (const float*)d_in[6];
    const float* Wo     = (const float*)d_in[7];
    const float* bq     = (const float*)d_in[8];
    const float* bk     = (const float*)d_in[9];
    const float* bv     = (const float*)d_in[10];
    const float* bo     = (const float*)d_in[11];
    const float* wi     = (const float*)d_in[12];
    const float* bi     = (const float*)d_in[13];
    const float* wf     = (const float*)d_in[14];
    const float* bf     = (const float*)d_in[15];

    float* out   = (float*)d_out;
    float* h_out = out;                       // [H]
    float* C_out = out + H;                   // [H*H]
    float* n_out = out + H + (size_t)H * H;   // [H]

    float* ws = (float*)d_ws;
    float* q  = ws;
    float* k  = ws + H;
    float* v  = ws + 2 * H;
    float* og = ws + 3 * H;
    float* u  = ws + 4 * H;
    float* s2 = ws + 5 * H;                   // 2 floats

    // Kernel 1: 2048 row-blocks (8 rows each) + 1 block for wi/wf dots.
    gemv_all<<<NB1 + 1, T1, 0, stream>>>(x, Wq, Wk, Wv, Wo, bq, bk, bv, bo,
                                         wi, wf, q, k, v, og, s2);

    // Kernel 2: 512 row-blocks (8 rows each).
    c_update<<<H / RPB, T1, 0, stream>>>(C_prev, q, k, v, s2, bi, bf, C_out, u);

    // Kernel 3: single block epilogue.
    finalize<<<1, 1024, 0, stream>>>(n_prev, q, k, v, og, u, s2, bi, bf,
                                     h_out, n_out);
}

// Round 3
// 336.417 us; speedup vs baseline: 1.0343x; 1.0343x over previous
//
#include <hip/hip_runtime.h>
#include <math.h>

#define H 4096
#define H4 (H / 4)          // 1024 float4 per row

typedef float f4 __attribute__((ext_vector_type(4)));   // NT-builtin-compatible

__device__ __forceinline__ float wave_reduce_sum(float v) {
    #pragma unroll
    for (int off = 32; off > 0; off >>= 1)
        v += __shfl_down(v, off, 64);
    return v;
}

__device__ __forceinline__ float sigmoidf_(float x) {
    return 1.0f / (1.0f + __expf(-x));
}

__device__ __forceinline__ float dot4(f4 a, f4 b) {
    return a.x * b.x + a.y * b.y + a.z * b.z + a.w * b.w;
}

// Kernel 1: all four GEMVs + the two scalar-gate dot products.
// One wave per output row; the full 16-float4 row is issued as two 8-load
// clauses fenced with sched_barrier(0) so the compiler cannot narrow the
// in-flight depth. x staged in LDS (ds_read doesn't touch vmcnt).
__global__ __launch_bounds__(256) void gemv_all(
    const float* __restrict__ x,
    const float* __restrict__ Wq, const float* __restrict__ Wk,
    const float* __restrict__ Wv, const float* __restrict__ Wo,
    const float* __restrict__ bq, const float* __restrict__ bk,
    const float* __restrict__ bv, const float* __restrict__ bo,
    const float* __restrict__ wi, const float* __restrict__ wf,
    float* __restrict__ q, float* __restrict__ k,
    float* __restrict__ v, float* __restrict__ og,
    float* __restrict__ s2)
{
    const int tid  = threadIdx.x;
    const int wave = tid >> 6;
    const int lane = tid & 63;

    __shared__ f4 xs[H4];                 // 16 KB
    const f4* x4 = (const f4*)x;
    #pragma unroll
    for (int i = 0; i < 4; ++i) xs[tid + i * 256] = x4[tid + i * 256];
    __syncthreads();

    const int rowId = blockIdx.x * 4 + wave;
    if (rowId >= 4 * H + 2) return;

    const int m = rowId >> 12;                // which matrix (0..3) when < 16384
    const int r = rowId & (H - 1);

    const float* row;
    if (rowId < 4 * H) {
        const float* W = (m == 0) ? Wq : (m == 1) ? Wk : (m == 2) ? Wv : Wo;
        row = W + (size_t)r * H;
    } else {
        row = (rowId == 4 * H) ? wi : wf;
    }
    const f4* row4 = (const f4*)row;

    // ---- clause 1: 8 loads issued back-to-back, fenced ----
    f4 a0 = row4[lane +   0];
    f4 a1 = row4[lane +  64];
    f4 a2 = row4[lane + 128];
    f4 a3 = row4[lane + 192];
    f4 a4_ = row4[lane + 256];
    f4 a5 = row4[lane + 320];
    f4 a6 = row4[lane + 384];
    f4 a7 = row4[lane + 448];
    __builtin_amdgcn_sched_barrier(0);
    // ---- clause 2: next 8 loads, also fenced before any consume ----
    f4 b0 = row4[lane + 512];
    f4 b1 = row4[lane + 576];
    f4 b2 = row4[lane + 640];
    f4 b3 = row4[lane + 704];
    f4 b4_ = row4[lane + 768];
    f4 b5 = row4[lane + 832];
    f4 b6 = row4[lane + 896];
    f4 b7 = row4[lane + 960];
    __builtin_amdgcn_sched_barrier(0);

    float s = 0.0f;
    s += dot4(a0,  xs[lane +   0]);
    s += dot4(a1,  xs[lane +  64]);
    s += dot4(a2,  xs[lane + 128]);
    s += dot4(a3,  xs[lane + 192]);
    s += dot4(a4_, xs[lane + 256]);
    s += dot4(a5,  xs[lane + 320]);
    s += dot4(a6,  xs[lane + 384]);
    s += dot4(a7,  xs[lane + 448]);
    s += dot4(b0,  xs[lane + 512]);
    s += dot4(b1,  xs[lane + 576]);
    s += dot4(b2,  xs[lane + 640]);
    s += dot4(b3,  xs[lane + 704]);
    s += dot4(b4_, xs[lane + 768]);
    s += dot4(b5,  xs[lane + 832]);
    s += dot4(b6,  xs[lane + 896]);
    s += dot4(b7,  xs[lane + 960]);

    s = wave_reduce_sum(s);

    if (lane == 0) {
        if (rowId < 4 * H) {
            if (m == 0)      q[r]  = s + bq[r];
            else if (m == 1) k[r]  = (s + bk[r]) * 0.015625f;  // 1/sqrt(4096)
            else if (m == 2) v[r]  = s + bv[r];
            else             og[r] = sigmoidf_(s + bo[r]);
        } else {
            s2[rowId - 4 * H] = s;   // s2[0] = wi.x, s2[1] = wf.x (raw dots)
        }
    }
}

// Kernel 2: C = f*C_prev + (i*v[r])*k  (streamed out with NT stores), and
// u[r] = C_prev[r,:] . q from the same loads.
// One wave per row; same forced two-clause structure; q,k staged in LDS.
// C_prev is dead after the read -> NT loads. C_out is never read -> NT
// stores (stop polluting L3, keep W resident for gemv_all next iteration).
__global__ __launch_bounds__(256) void c_update(
    const float* __restrict__ C_prev,
    const float* __restrict__ q, const float* __restrict__ k,
    const float* __restrict__ v, const float* __restrict__ s2,
    const float* __restrict__ bi, const float* __restrict__ bf,
    float* __restrict__ C_out, float* __restrict__ u)
{
    const int tid  = threadIdx.x;
    const int wave = tid >> 6;
    const int lane = tid & 63;

    __shared__ f4 qs[H4];                 // 16 KB
    __shared__ f4 ks[H4];                 // 16 KB
    const f4* q4 = (const f4*)q;
    const f4* k4 = (const f4*)k;
    #pragma unroll
    for (int i = 0; i < 4; ++i) {
        qs[tid + i * 256] = q4[tid + i * 256];
        ks[tid + i * 256] = k4[tid + i * 256];
    }
    __syncthreads();

    const int r = blockIdx.x * 4 + wave;

    const float ig  = __expf(s2[0] + bi[0]);
    const float fg  = sigmoidf_(s2[1] + bf[0]);
    const float ivr = ig * v[r];

    const f4* c4 = (const f4*)(C_prev + (size_t)r * H);
    f4*       o4 = (f4*)(C_out + (size_t)r * H);

    // ---- clause 1 ----
    f4 a0 = __builtin_nontemporal_load(&c4[lane +   0]);
    f4 a1 = __builtin_nontemporal_load(&c4[lane +  64]);
    f4 a2 = __builtin_nontemporal_load(&c4[lane + 128]);
    f4 a3 = __builtin_nontemporal_load(&c4[lane + 192]);
    f4 a4_ = __builtin_nontemporal_load(&c4[lane + 256]);
    f4 a5 = __builtin_nontemporal_load(&c4[lane + 320]);
    f4 a6 = __builtin_nontemporal_load(&c4[lane + 384]);
    f4 a7 = __builtin_nontemporal_load(&c4[lane + 448]);
    __builtin_amdgcn_sched_barrier(0);
    // ---- clause 2 ----
    f4 b0 = __builtin_nontemporal_load(&c4[lane + 512]);
    f4 b1 = __builtin_nontemporal_load(&c4[lane + 576]);
    f4 b2 = __builtin_nontemporal_load(&c4[lane + 640]);
    f4 b3 = __builtin_nontemporal_load(&c4[lane + 704]);
    f4 b4_ = __builtin_nontemporal_load(&c4[lane + 768]);
    f4 b5 = __builtin_nontemporal_load(&c4[lane + 832]);
    f4 b6 = __builtin_nontemporal_load(&c4[lane + 896]);
    f4 b7 = __builtin_nontemporal_load(&c4[lane + 960]);
    __builtin_amdgcn_sched_barrier(0);

    float acc = 0.0f;
    f4 o;
    #define CONSUME(reg, off)                                            \
        {                                                                \
            f4 kk = ks[lane + (off)];                                    \
            o.x = fg * reg.x + ivr * kk.x;                               \
            o.y = fg * reg.y + ivr * kk.y;                               \
            o.z = fg * reg.z + ivr * kk.z;                               \
            o.w = fg * reg.w + ivr * kk.w;                               \
            __builtin_nontemporal_store(o, &o4[lane + (off)]);           \
            acc += dot4(reg, qs[lane + (off)]);                          \
        }
    CONSUME(a0,   0) CONSUME(a1,  64) CONSUME(a2, 128) CONSUME(a3, 192)
    CONSUME(a4_, 256) CONSUME(a5, 320) CONSUME(a6, 384) CONSUME(a7, 448)
    CONSUME(b0, 512) CONSUME(b1, 576) CONSUME(b2, 640) CONSUME(b3, 704)
    CONSUME(b4_, 768) CONSUME(b5, 832) CONSUME(b6, 896) CONSUME(b7, 960)
    #undef CONSUME

    acc = wave_reduce_sum(acc);
    if (lane == 0) u[r] = acc;
}

// Kernel 3: n = f*n_prev + i*k (written out); nq = n.q; kq = k.q;
// h = og * (f*u + i*v*kq) / max(|nq|,1). Single block.
__global__ __launch_bounds__(1024) void finalize(
    const float* __restrict__ n_prev,
    const float* __restrict__ q, const float* __restrict__ k,
    const float* __restrict__ v, const float* __restrict__ og,
    const float* __restrict__ u, const float* __restrict__ s2,
    const float* __restrict__ bi, const float* __restrict__ bf,
    float* __restrict__ h, float* __restrict__ n_out)
{
    const int t = threadIdx.x;
    const int wave = t >> 6;
    const int lane = t & 63;

    const float ig = __expf(s2[0] + bi[0]);
    const float fg = sigmoidf_(s2[1] + bf[0]);

    float nq = 0.0f, kq = 0.0f;
    for (int j = t; j < H; j += 1024) {
        float kj = k[j];
        float qj = q[j];
        float nj = fg * n_prev[j] + ig * kj;
        n_out[j] = nj;
        nq += nj * qj;
        kq += kj * qj;
    }
    nq = wave_reduce_sum(nq);
    kq = wave_reduce_sum(kq);

    __shared__ float snq[16], skq[16];
    if (lane == 0) { snq[wave] = nq; skq[wave] = kq; }
    __syncthreads();
    if (t == 0) {
        float a = 0.0f, b = 0.0f;
        #pragma unroll
        for (int w = 0; w < 16; ++w) { a += snq[w]; b += skq[w]; }
        snq[0] = a; skq[0] = b;
    }
    __syncthreads();

    const float denom = fmaxf(fabsf(snq[0]), 1.0f);
    const float kqv = skq[0];
    const float inv_denom = 1.0f / denom;

    for (int j = t; j < H; j += 1024) {
        float ht = (fg * u[j] + ig * v[j] * kqv) * inv_denom;
        h[j] = og[j] * ht;
    }
}

extern "C" void kernel_launch(void* const* d_in, const int* in_sizes, int n_in,
                              void* d_out, int out_size, void* d_ws, size_t ws_size,
                              hipStream_t stream) {
    const float* x      = (const float*)d_in[0];
    // d_in[1] = h_prev (unused by mLSTM math)
    const float* C_prev = (const float*)d_in[2];
    const float* n_prev = (const float*)d_in[3];
    const float* Wq     = (const float*)d_in[4];
    const float* Wk     = (const float*)d_in[5];
    const float* Wv     = (const float*)d_in[6];
    const float* Wo     = (const float*)d_in[7];
    const float* bq     = (const float*)d_in[8];
    const float* bk     = (const float*)d_in[9];
    const float* bv     = (const float*)d_in[10];
    const float* bo     = (const float*)d_in[11];
    const float* wi     = (const float*)d_in[12];
    const float* bi     = (const float*)d_in[13];
    const float* wf     = (const float*)d_in[14];
    const float* bf     = (const float*)d_in[15];

    float* out   = (float*)d_out;
    float* h_out = out;                       // [H]
    float* C_out = out + H;                   // [H*H]
    float* n_out = out + H + (size_t)H * H;   // [H]

    float* ws = (float*)d_ws;
    float* q  = ws;
    float* k  = ws + H;
    float* v  = ws + 2 * H;
    float* og = ws + 3 * H;
    float* u  = ws + 4 * H;
    float* s2 = ws + 5 * H;                   // 2 floats

    // Kernel 1: 4*H rows + 2 dot rows, one wave per row, 4 waves per block.
    const int nrows = 4 * H + 2;
    const int blocks1 = (nrows + 3) / 4;
    gemv_all<<<blocks1, 256, 0, stream>>>(x, Wq, Wk, Wv, Wo, bq, bk, bv, bo,
                                          wi, wf, q, k, v, og, s2);

    // Kernel 2: H rows, one wave per row.
    c_update<<<H / 4, 256, 0, stream>>>(C_prev, q, k, v, s2, bi, bf, C_out, u);

    // Kernel 3: single block epilogue.
    finalize<<<1, 1024, 0, stream>>>(n_prev, q, k, v, og, u, s2, bi, bf,
                                     h_out, n_out);
}

// Round 4
// 314.670 us; speedup vs baseline: 1.1058x; 1.0691x over previous
//
#include <hip/hip_runtime.h>
#include <math.h>

#define H 4096
#define H4 (H / 4)          // 1024 float4 per row

typedef float f4 __attribute__((ext_vector_type(4)));   // NT-builtin-compatible

__device__ __forceinline__ float wave_reduce_sum(float v) {
    #pragma unroll
    for (int off = 32; off > 0; off >>= 1)
        v += __shfl_down(v, off, 64);
    return v;
}

__device__ __forceinline__ float sigmoidf_(float x) {
    return 1.0f / (1.0f + __expf(-x));
}

__device__ __forceinline__ float dot4(f4 a, f4 b) {
    return a.x * b.x + a.y * b.y + a.z * b.z + a.w * b.w;
}

// Kernel 1: all four GEMVs + the two scalar-gate dot products.
// One wave per output row, 16 waves (1024 threads) per block for full
// occupancy. W rows are read with NONTEMPORAL loads: W is single-pass
// within an iteration and only ~50% L3-resident across iterations; the
// L3 lookup path is the suspected ~2.8 TB/s cap, so stream W straight
// from HBM and leave L3 to x/q/k/C traffic.
__global__ __launch_bounds__(1024) void gemv_all(
    const float* __restrict__ x,
    const float* __restrict__ Wq, const float* __restrict__ Wk,
    const float* __restrict__ Wv, const float* __restrict__ Wo,
    const float* __restrict__ bq, const float* __restrict__ bk,
    const float* __restrict__ bv, const float* __restrict__ bo,
    const float* __restrict__ wi, const float* __restrict__ wf,
    float* __restrict__ q, float* __restrict__ k,
    float* __restrict__ v, float* __restrict__ og,
    float* __restrict__ s2)
{
    const int tid  = threadIdx.x;
    const int wave = tid >> 6;
    const int lane = tid & 63;

    __shared__ f4 xs[H4];                 // 16 KB, one stage for 16 rows
    const f4* x4 = (const f4*)x;
    xs[tid] = x4[tid];
    __syncthreads();

    const int rowId = blockIdx.x * 16 + wave;
    if (rowId >= 4 * H + 2) return;

    const int m = rowId >> 12;                // which matrix (0..3) when < 16384
    const int r = rowId & (H - 1);

    const float* row;
    if (rowId < 4 * H) {
        const float* W = (m == 0) ? Wq : (m == 1) ? Wk : (m == 2) ? Wv : Wo;
        row = W + (size_t)r * H;
    } else {
        row = (rowId == 4 * H) ? wi : wf;
    }
    const f4* row4 = (const f4*)row;

    float s = 0.0f;
    #pragma unroll
    for (int half = 0; half < 2; ++half) {
        const int base = half * 512;
        // 8 NT loads issued as a group, then consumed
        f4 a0 = __builtin_nontemporal_load(&row4[lane + base +   0]);
        f4 a1 = __builtin_nontemporal_load(&row4[lane + base +  64]);
        f4 a2 = __builtin_nontemporal_load(&row4[lane + base + 128]);
        f4 a3 = __builtin_nontemporal_load(&row4[lane + base + 192]);
        f4 a4_ = __builtin_nontemporal_load(&row4[lane + base + 256]);
        f4 a5 = __builtin_nontemporal_load(&row4[lane + base + 320]);
        f4 a6 = __builtin_nontemporal_load(&row4[lane + base + 384]);
        f4 a7 = __builtin_nontemporal_load(&row4[lane + base + 448]);
        s += dot4(a0,  xs[lane + base +   0]);
        s += dot4(a1,  xs[lane + base +  64]);
        s += dot4(a2,  xs[lane + base + 128]);
        s += dot4(a3,  xs[lane + base + 192]);
        s += dot4(a4_, xs[lane + base + 256]);
        s += dot4(a5,  xs[lane + base + 320]);
        s += dot4(a6,  xs[lane + base + 384]);
        s += dot4(a7,  xs[lane + base + 448]);
    }

    s = wave_reduce_sum(s);

    if (lane == 0) {
        if (rowId < 4 * H) {
            if (m == 0)      q[r]  = s + bq[r];
            else if (m == 1) k[r]  = (s + bk[r]) * 0.015625f;  // 1/sqrt(4096)
            else if (m == 2) v[r]  = s + bv[r];
            else             og[r] = sigmoidf_(s + bo[r]);
        } else {
            s2[rowId - 4 * H] = s;   // s2[0] = wi.x, s2[1] = wf.x (raw dots)
        }
    }
}

// Kernel 2: C = f*C_prev + (i*v[r])*k  (NT stores), and
// u[r] = C_prev[r,:] . q from the same NT loads. Unchanged from round 3.
__global__ __launch_bounds__(256) void c_update(
    const float* __restrict__ C_prev,
    const float* __restrict__ q, const float* __restrict__ k,
    const float* __restrict__ v, const float* __restrict__ s2,
    const float* __restrict__ bi, const float* __restrict__ bf,
    float* __restrict__ C_out, float* __restrict__ u)
{
    const int tid  = threadIdx.x;
    const int wave = tid >> 6;
    const int lane = tid & 63;

    __shared__ f4 qs[H4];                 // 16 KB
    __shared__ f4 ks[H4];                 // 16 KB
    const f4* q4 = (const f4*)q;
    const f4* k4 = (const f4*)k;
    #pragma unroll
    for (int i = 0; i < 4; ++i) {
        qs[tid + i * 256] = q4[tid + i * 256];
        ks[tid + i * 256] = k4[tid + i * 256];
    }
    __syncthreads();

    const int r = blockIdx.x * 4 + wave;

    const float ig  = __expf(s2[0] + bi[0]);
    const float fg  = sigmoidf_(s2[1] + bf[0]);
    const float ivr = ig * v[r];

    const f4* c4 = (const f4*)(C_prev + (size_t)r * H);
    f4*       o4 = (f4*)(C_out + (size_t)r * H);

    float acc = 0.0f;
    #pragma unroll
    for (int half = 0; half < 2; ++half) {
        const int base = half * 512;
        f4 a0 = __builtin_nontemporal_load(&c4[lane + base +   0]);
        f4 a1 = __builtin_nontemporal_load(&c4[lane + base +  64]);
        f4 a2 = __builtin_nontemporal_load(&c4[lane + base + 128]);
        f4 a3 = __builtin_nontemporal_load(&c4[lane + base + 192]);
        f4 a4_ = __builtin_nontemporal_load(&c4[lane + base + 256]);
        f4 a5 = __builtin_nontemporal_load(&c4[lane + base + 320]);
        f4 a6 = __builtin_nontemporal_load(&c4[lane + base + 384]);
        f4 a7 = __builtin_nontemporal_load(&c4[lane + base + 448]);

        f4 o;
        #define CONSUME(reg, off)                                        \
            {                                                            \
                f4 kk = ks[lane + (off)];                                \
                o.x = fg * reg.x + ivr * kk.x;                           \
                o.y = fg * reg.y + ivr * kk.y;                           \
                o.z = fg * reg.z + ivr * kk.z;                           \
                o.w = fg * reg.w + ivr * kk.w;                           \
                __builtin_nontemporal_store(o, &o4[lane + (off)]);       \
                acc += dot4(reg, qs[lane + (off)]);                      \
            }
        CONSUME(a0, base +   0) CONSUME(a1, base +  64)
        CONSUME(a2, base + 128) CONSUME(a3, base + 192)
        CONSUME(a4_, base + 256) CONSUME(a5, base + 320)
        CONSUME(a6, base + 384) CONSUME(a7, base + 448)
        #undef CONSUME
    }

    acc = wave_reduce_sum(acc);
    if (lane == 0) u[r] = acc;
}

// Kernel 3: n = f*n_prev + i*k (written out); nq = n.q; kq = k.q;
// h = og * (f*u + i*v*kq) / max(|nq|,1). Single block.
__global__ __launch_bounds__(1024) void finalize(
    const float* __restrict__ n_prev,
    const float* __restrict__ q, const float* __restrict__ k,
    const float* __restrict__ v, const float* __restrict__ og,
    const float* __restrict__ u, const float* __restrict__ s2,
    const float* __restrict__ bi, const float* __restrict__ bf,
    float* __restrict__ h, float* __restrict__ n_out)
{
    const int t = threadIdx.x;
    const int wave = t >> 6;
    const int lane = t & 63;

    const float ig = __expf(s2[0] + bi[0]);
    const float fg = sigmoidf_(s2[1] + bf[0]);

    float nq = 0.0f, kq = 0.0f;
    for (int j = t; j < H; j += 1024) {
        float kj = k[j];
        float qj = q[j];
        float nj = fg * n_prev[j] + ig * kj;
        n_out[j] = nj;
        nq += nj * qj;
        kq += kj * qj;
    }
    nq = wave_reduce_sum(nq);
    kq = wave_reduce_sum(kq);

    __shared__ float snq[16], skq[16];
    if (lane == 0) { snq[wave] = nq; skq[wave] = kq; }
    __syncthreads();
    if (t == 0) {
        float a = 0.0f, b = 0.0f;
        #pragma unroll
        for (int w = 0; w < 16; ++w) { a += snq[w]; b += skq[w]; }
        snq[0] = a; skq[0] = b;
    }
    __syncthreads();

    const float denom = fmaxf(fabsf(snq[0]), 1.0f);
    const float kqv = skq[0];
    const float inv_denom = 1.0f / denom;

    for (int j = t; j < H; j += 1024) {
        float ht = (fg * u[j] + ig * v[j] * kqv) * inv_denom;
        h[j] = og[j] * ht;
    }
}

extern "C" void kernel_launch(void* const* d_in, const int* in_sizes, int n_in,
                              void* d_out, int out_size, void* d_ws, size_t ws_size,
                              hipStream_t stream) {
    const float* x      = (const float*)d_in[0];
    // d_in[1] = h_prev (unused by mLSTM math)
    const float* C_prev = (const float*)d_in[2];
    const float* n_prev = (const float*)d_in[3];
    const float* Wq     = (const float*)d_in[4];
    const float* Wk     = (const float*)d_in[5];
    const float* Wv     = (const float*)d_in[6];
    const float* Wo     = (const float*)d_in[7];
    const float* bq     = (const float*)d_in[8];
    const float* bk     = (const float*)d_in[9];
    const float* bv     = (const float*)d_in[10];
    const float* bo     = (const float*)d_in[11];
    const float* wi     = (const float*)d_in[12];
    const float* bi     = (const float*)d_in[13];
    const float* wf     = (const float*)d_in[14];
    const float* bf     = (const float*)d_in[15];

    float* out   = (float*)d_out;
    float* h_out = out;                       // [H]
    float* C_out = out + H;                   // [H*H]
    float* n_out = out + H + (size_t)H * H;   // [H]

    float* ws = (float*)d_ws;
    float* q  = ws;
    float* k  = ws + H;
    float* v  = ws + 2 * H;
    float* og = ws + 3 * H;
    float* u  = ws + 4 * H;
    float* s2 = ws + 5 * H;                   // 2 floats

    // Kernel 1: 4*H+2 rows, one wave per row, 16 waves per block.
    const int nrows = 4 * H + 2;
    const int blocks1 = (nrows + 15) / 16;
    gemv_all<<<blocks1, 1024, 0, stream>>>(x, Wq, Wk, Wv, Wo, bq, bk, bv, bo,
                                           wi, wf, q, k, v, og, s2);

    // Kernel 2: H rows, one wave per row.
    c_update<<<H / 4, 256, 0, stream>>>(C_prev, q, k, v, s2, bi, bf, C_out, u);

    // Kernel 3: single block epilogue.
    finalize<<<1, 1024, 0, stream>>>(n_prev, q, k, v, og, u, s2, bi, bf,
                                     h_out, n_out);
}